// Round 1
// baseline (1197.925 us; speedup 1.0000x reference)
//
#include <hip/hip_runtime.h>

// MaskedBatchNorm2d: B=16, C=64, W=256, H=256, fp32.
// Key identity: masked-out locations are exactly zero in all channels, so
// per-channel masked sums == full sums, and out = x * inv[c] everywhere
// (dirty-cancellation locations handled by a never-taken slow path).

#define NB 16
#define CB 64
#define WH 65536          // W*H
#define TILE 256          // locations per tile (block-wide)
#define NTILES (NB * WH / TILE)   // 4096
#define DIRTY_CAP 512
#define EPS 0.001f

// ws layout (4-byte units):
//  [0..63]   float S[64]      (zeroed)
//  [64..127] float Q[64]      (zeroed)
//  [128..143] uint n[16]      (zeroed)
//  [144]     uint dirtyCount  (zeroed)
//  [160..223] float inv[64]   (written by finalize)
//  [224..239] int  pad[16]    (written by finalize)
//  [256..767] int  dirtyLoc[DIRTY_CAP]

__global__ __launch_bounds__(256, 4)
void mbn_pass1(const float* __restrict__ x, float* __restrict__ S, float* __restrict__ Q,
               unsigned* __restrict__ nCnt, unsigned* __restrict__ dirtyCnt,
               int* __restrict__ dirtyLoc) {
    __shared__ float lds_s[4][TILE];
    __shared__ float lds_a[4][TILE];
    const int tid  = threadIdx.x;
    const int wave = tid >> 6;
    const int lane = tid & 63;

    float sAcc[16], qAcc[16];
#pragma unroll
    for (int j = 0; j < 16; ++j) { sAcc[j] = 0.f; qAcc[j] = 0.f; }

    for (int tile = blockIdx.x; tile < NTILES; tile += gridDim.x) {
        const int b   = tile >> 8;              // 256 tiles per batch
        const int whb = (tile & 255) * TILE;
        const float* base = x + (((size_t)(b * 64 + wave * 16)) << 16) + whb + lane * 4;

        float sp0 = 0.f, sp1 = 0.f, sp2 = 0.f, sp3 = 0.f;
        float aa0 = 0.f, aa1 = 0.f, aa2 = 0.f, aa3 = 0.f;
#pragma unroll
        for (int j = 0; j < 16; ++j) {
            float4 v = *(const float4*)(base + ((size_t)j << 16));
            sp0 += v.x; sp1 += v.y; sp2 += v.z; sp3 += v.w;
            aa0 += fabsf(v.x); aa1 += fabsf(v.y); aa2 += fabsf(v.z); aa3 += fabsf(v.w);
            sAcc[j] += (v.x + v.y) + (v.z + v.w);
            qAcc[j] = fmaf(v.x, v.x, qAcc[j]);
            qAcc[j] = fmaf(v.y, v.y, qAcc[j]);
            qAcc[j] = fmaf(v.z, v.z, qAcc[j]);
            qAcc[j] = fmaf(v.w, v.w, qAcc[j]);
        }
        *(float4*)&lds_s[wave][lane * 4] = make_float4(sp0, sp1, sp2, sp3);
        *(float4*)&lds_a[wave][lane * 4] = make_float4(aa0, aa1, aa2, aa3);
        __syncthreads();

        // thread t owns location t of the tile: combine 4 waves' channel-partials
        float s = lds_s[0][tid] + lds_s[1][tid] + lds_s[2][tid] + lds_s[3][tid];
        float a = lds_a[0][tid] + lds_a[1][tid] + lds_a[2][tid] + lds_a[3][tid];
        bool mask = (s != 0.0f);
        unsigned long long bal = __ballot(mask);
        if (lane == 0) atomicAdd(&nCnt[b], (unsigned)__popcll(bal));
        if (!mask && a != 0.0f) {                     // exact cancellation: ~never
            unsigned idx = atomicAdd(dirtyCnt, 1u);
            if (idx < DIRTY_CAP) dirtyLoc[idx] = (b << 16) | (whb + tid);
        }
        __syncthreads();
    }

    // end-of-kernel: reduce register accumulators across the wave, one atomic/channel
#pragma unroll
    for (int j = 0; j < 16; ++j) {
        float sv = sAcc[j], qv = qAcc[j];
        for (int off = 32; off; off >>= 1) {
            sv += __shfl_xor(sv, off);
            qv += __shfl_xor(qv, off);
        }
        if (lane == 0) {
            atomicAdd(&S[wave * 16 + j], sv);
            atomicAdd(&Q[wave * 16 + j], qv);
        }
    }
}

__global__ void mbn_finalize(const float* __restrict__ x, const float* __restrict__ S,
                             const float* __restrict__ Q, const unsigned* __restrict__ nCnt,
                             const unsigned* __restrict__ dirtyCnt, const int* __restrict__ dirtyLoc,
                             float* __restrict__ inv, int* __restrict__ padOut) {
    const int c = threadIdx.x;   // 64 threads, one per channel
    unsigned nmax = 0;
#pragma unroll
    for (int b = 0; b < NB; ++b) { unsigned nb = nCnt[b]; nmax = nb > nmax ? nb : nmax; }
    const float total = (float)(16u * nmax);   // B*Nmax, exact in fp32 (<2^24)

    float s = S[c], q = Q[c];
    // dirty corrections (reference excludes cancellation locations) — ~never runs
    unsigned cnt = *dirtyCnt; if (cnt > DIRTY_CAP) cnt = DIRTY_CAP;
    for (unsigned i = 0; i < cnt; ++i) {
        int loc = dirtyLoc[i];
        int b = loc >> 16, wh = loc & 65535;
        float v = x[(((size_t)(b * 64 + c)) << 16) + wh];
        s -= v; q -= v * v;
    }
    float p1 = 0.f, p2 = 0.f;
#pragma unroll
    for (int b = 0; b < NB; ++b) {
        float padf = (float)(nmax - nCnt[b]);
        float v00  = x[((size_t)(b * 64 + c)) << 16];
        p1 = fmaf(padf, v00, p1);
        p2 = fmaf(padf, v00 * v00, p2);
        if (c == 0) padOut[b] = (int)(nmax - nCnt[b]);
    }
    float mean = (s + p1) / total;
    float var  = (q + p2) / total - mean * mean;   // exact algebraic identity w/ ref
    inv[c] = 1.0f / sqrtf(var + EPS);
}

__global__ __launch_bounds__(256)
void mbn_pass2(const float4* __restrict__ x4, float4* __restrict__ out4,
               const float* __restrict__ inv) {
    size_t i = (size_t)blockIdx.x * blockDim.x + threadIdx.x;  // 16,777,216 float4s
    int c = (int)((i >> 14) & 63);                             // 16384 float4 per plane
    float sc = inv[c];
    float4 v = x4[i];
    v.x *= sc; v.y *= sc; v.z *= sc; v.w *= sc;
    out4[i] = v;
}

__global__ void mbn_fixup(const float* __restrict__ x, float* __restrict__ out,
                          const unsigned* __restrict__ dirtyCnt, const int* __restrict__ dirtyLoc,
                          const int* __restrict__ padArr) {
    const int c = threadIdx.x;  // 64
    unsigned cnt = *dirtyCnt; if (cnt > DIRTY_CAP) cnt = DIRTY_CAP;
    for (unsigned i = 0; i < cnt; ++i) {
        int loc = dirtyLoc[i];
        int b = loc >> 16, wh = loc & 65535;
        if (wh == 0 && padArr[b] > 0) continue;   // (0,0) override wins: keep x00*inv
        size_t idx = (((size_t)(b * 64 + c)) << 16) + wh;
        out[idx] = x[idx];                        // m=0 location with nonzero x: out = x
    }
}

extern "C" void kernel_launch(void* const* d_in, const int* in_sizes, int n_in,
                              void* d_out, int out_size, void* d_ws, size_t ws_size,
                              hipStream_t stream) {
    const float* x = (const float*)d_in[0];
    float* out = (float*)d_out;
    float* wsf = (float*)d_ws;

    float*    S        = wsf;
    float*    Q        = wsf + 64;
    unsigned* nCnt     = (unsigned*)(wsf + 128);
    unsigned* dirtyCnt = (unsigned*)(wsf + 144);
    float*    inv      = wsf + 160;
    int*      padArr   = (int*)(wsf + 224);
    int*      dirtyLoc = (int*)(wsf + 256);

    size_t zb = ws_size < 4096 ? ws_size : 4096;
    hipMemsetAsync(d_ws, 0, zb, stream);

    mbn_pass1<<<2048, 256, 0, stream>>>(x, S, Q, nCnt, dirtyCnt, dirtyLoc);
    mbn_finalize<<<1, 64, 0, stream>>>(x, S, Q, nCnt, dirtyCnt, dirtyLoc, inv, padArr);
    mbn_pass2<<<65536, 256, 0, stream>>>((const float4*)x, (float4*)out, inv);
    mbn_fixup<<<1, 64, 0, stream>>>(x, out, dirtyCnt, dirtyLoc, padArr);
}

// Round 2
// 592.380 us; speedup vs baseline: 2.0222x; 2.0222x over previous
//
#include <hip/hip_runtime.h>

// MaskedBatchNorm2d: B=16, C=64, W=256, H=256, fp32.
// Identity: masked-out locations are exactly 0 in all channels, so masked
// per-channel sums == full sums and out = x*inv[c] everywhere (exact-
// cancellation "dirty" locations handled by a ~never-taken fixup path).
//
// R1 lesson: 262K same-line global fp32 atomics serialized pass1 at ~3ns/op
// (823us, 2% HBM peak). This version uses ZERO global atomics on the hot
// path: per-block partials -> plain stores -> one-block tree reduce.

#define NB 16
#define CB 64
#define WH 65536               // W*H
#define TILE 256               // locations per tile (block-wide)
#define NTILES (NB * WH / TILE)  // 4096
#define GRID1 1024
#define TPT (NTILES / GRID1)   // 4 tiles per block
#define DIRTY_CAP 512
#define EPS 0.001f

// ws layout (float units):
//  [0 .. 131071]        sqPart[GRID1][128]  (S row 0..63, Q row 64..127) - 512 KB
//  [131072 .. 147455]   nPart[GRID1][16]    (uint)                       -  64 KB
//  [147456]             dirtyCnt (uint, zeroed by memset)
//  [147520 .. 147583]   inv[64]
//  [147584 .. 147599]   padArr[16] (int)
//  [147600 .. 148111]   dirtyLoc[DIRTY_CAP] (int)

__global__ __launch_bounds__(256, 4)
void mbn_pass1(const float* __restrict__ x, float* __restrict__ sqPart,
               unsigned* __restrict__ nPart, unsigned* __restrict__ dirtyCnt,
               int* __restrict__ dirtyLoc) {
    __shared__ float lds_s[4][TILE];
    __shared__ float lds_a[4][TILE];
    __shared__ unsigned cnt_lds[16];
    const int tid  = threadIdx.x;
    const int wave = tid >> 6;
    const int lane = tid & 63;
    if (tid < 16) cnt_lds[tid] = 0;

    float sAcc[16], qAcc[16];
#pragma unroll
    for (int j = 0; j < 16; ++j) { sAcc[j] = 0.f; qAcc[j] = 0.f; }
    __syncthreads();

    for (int tt = 0; tt < TPT; ++tt) {
        const int tile = blockIdx.x + tt * GRID1;
        const int b    = tile >> 8;                 // 256 tiles per batch
        const int whb  = (tile & 255) * TILE;
        const float* base = x + (((size_t)(b * 64 + wave * 16)) << 16) + whb + lane * 4;

        float sp0 = 0.f, sp1 = 0.f, sp2 = 0.f, sp3 = 0.f;
        float aa0 = 0.f, aa1 = 0.f, aa2 = 0.f, aa3 = 0.f;
#pragma unroll
        for (int j = 0; j < 16; ++j) {
            float4 v = *(const float4*)(base + ((size_t)j << 16));
            sp0 += v.x; sp1 += v.y; sp2 += v.z; sp3 += v.w;
            aa0 += fabsf(v.x); aa1 += fabsf(v.y); aa2 += fabsf(v.z); aa3 += fabsf(v.w);
            sAcc[j] += (v.x + v.y) + (v.z + v.w);
            qAcc[j] = fmaf(v.x, v.x, qAcc[j]);
            qAcc[j] = fmaf(v.y, v.y, qAcc[j]);
            qAcc[j] = fmaf(v.z, v.z, qAcc[j]);
            qAcc[j] = fmaf(v.w, v.w, qAcc[j]);
        }
        *(float4*)&lds_s[wave][lane * 4] = make_float4(sp0, sp1, sp2, sp3);
        *(float4*)&lds_a[wave][lane * 4] = make_float4(aa0, aa1, aa2, aa3);
        __syncthreads();

        // thread t owns location t of the tile: combine the 4 waves' partials
        float s = lds_s[0][tid] + lds_s[1][tid] + lds_s[2][tid] + lds_s[3][tid];
        float a = lds_a[0][tid] + lds_a[1][tid] + lds_a[2][tid] + lds_a[3][tid];
        bool mask = (s != 0.0f);
        unsigned long long bal = __ballot(mask);
        if (lane == 0) atomicAdd(&cnt_lds[b], (unsigned)__popcll(bal));  // LDS atomic
        if (!mask && a != 0.0f) {                   // exact cancellation: ~never
            unsigned idx = atomicAdd(dirtyCnt, 1u);
            if (idx < DIRTY_CAP) dirtyLoc[idx] = (b << 16) | (whb + tid);
        }
        __syncthreads();
    }

    // wave-reduce register accumulators; plain stores to this block's ws row
#pragma unroll
    for (int j = 0; j < 16; ++j) {
        float sv = sAcc[j], qv = qAcc[j];
        for (int off = 32; off; off >>= 1) {
            sv += __shfl_xor(sv, off);
            qv += __shfl_xor(qv, off);
        }
        if (lane == 0) {
            sqPart[blockIdx.x * 128 + wave * 16 + j]      = sv;
            sqPart[blockIdx.x * 128 + 64 + wave * 16 + j] = qv;
        }
    }
    __syncthreads();
    if (tid < 16) nPart[blockIdx.x * 16 + tid] = cnt_lds[tid];
}

__global__ void mbn_finalize(const float* __restrict__ x, const float* __restrict__ sqPart,
                             const unsigned* __restrict__ nPart,
                             const unsigned* __restrict__ dirtyCnt, const int* __restrict__ dirtyLoc,
                             float* __restrict__ inv, int* __restrict__ padOut) {
    __shared__ float red[256];
    __shared__ float sq[128];
    __shared__ unsigned npar[4][16];
    __shared__ unsigned ntot[16];
    const int t = threadIdx.x;            // 256 threads
    const int idx = t & 127, half = t >> 7;

    // coalesced reduce of sqPart: thread t sums column idx over 512 block-rows
    float acc = 0.f;
    const float* p = sqPart + (size_t)half * 512 * 128 + idx;
#pragma unroll 8
    for (int blk = 0; blk < 512; ++blk) acc += p[(size_t)blk * 128];
    red[t] = acc;

    if (t >= 192) {                        // one wave reduces the mask counts
        const int b = t & 15, q = (t >> 4) & 3;   // q = 0..3
        unsigned s = 0;
        const unsigned* np = nPart + q * 256 * 16 + b;
#pragma unroll 8
        for (int blk = 0; blk < 256; ++blk) s += np[blk * 16];
        npar[q][b] = s;
    }
    __syncthreads();
    if (t < 128) sq[t] = red[t] + red[t + 128];
    if (t < 16)  ntot[t] = npar[0][t] + npar[1][t] + npar[2][t] + npar[3][t];
    __syncthreads();

    if (t < 64) {
        const int c = t;
        unsigned nmax = 0;
#pragma unroll
        for (int b = 0; b < NB; ++b) { unsigned nb = ntot[b]; nmax = nb > nmax ? nb : nmax; }
        const float total = (float)(16u * nmax);   // B*Nmax, exact in fp32

        float s = sq[c], q = sq[64 + c];
        // dirty corrections (exclude exact-cancellation locations) — ~never runs
        unsigned cnt = *dirtyCnt; if (cnt > DIRTY_CAP) cnt = DIRTY_CAP;
        for (unsigned i = 0; i < cnt; ++i) {
            int loc = dirtyLoc[i];
            int b = loc >> 16, wh = loc & 65535;
            float v = x[(((size_t)(b * 64 + c)) << 16) + wh];
            s -= v; q -= v * v;
        }
        float p1 = 0.f, p2 = 0.f;
#pragma unroll
        for (int b = 0; b < NB; ++b) {
            float padf = (float)(nmax - ntot[b]);
            float v00  = x[((size_t)(b * 64 + c)) << 16];
            p1 = fmaf(padf, v00, p1);
            p2 = fmaf(padf, v00 * v00, p2);
            if (c == 0) padOut[b] = (int)(nmax - ntot[b]);
        }
        float mean = (s + p1) / total;
        float var  = (q + p2) / total - mean * mean;   // algebraic identity w/ ref
        inv[c] = 1.0f / sqrtf(var + EPS);
    }
}

__global__ __launch_bounds__(256)
void mbn_pass2(const float4* __restrict__ x4, float4* __restrict__ out4,
               const float* __restrict__ inv) {
    // 8192 blocks x 2048 float4: each block's chunk lies in ONE channel plane
    const int blk = blockIdx.x;
    const float sc = inv[(blk >> 3) & 63];             // 8 blocks per plane
    const size_t base = (size_t)blk * 2048 + threadIdx.x;
#pragma unroll
    for (int k = 0; k < 8; ++k) {
        size_t i = base + (size_t)k * 256;
        float4 v = x4[i];
        v.x *= sc; v.y *= sc; v.z *= sc; v.w *= sc;
        out4[i] = v;
    }
}

__global__ void mbn_fixup(const float* __restrict__ x, float* __restrict__ out,
                          const unsigned* __restrict__ dirtyCnt, const int* __restrict__ dirtyLoc,
                          const int* __restrict__ padArr) {
    const int c = threadIdx.x;  // 64
    unsigned cnt = *dirtyCnt; if (cnt > DIRTY_CAP) cnt = DIRTY_CAP;
    for (unsigned i = 0; i < cnt; ++i) {
        int loc = dirtyLoc[i];
        int b = loc >> 16, wh = loc & 65535;
        if (wh == 0 && padArr[b] > 0) continue;   // (0,0) override wins: keep x00*inv
        size_t idx = (((size_t)(b * 64 + c)) << 16) + wh;
        out[idx] = x[idx];                        // m=0 location w/ nonzero x: out = x
    }
}

extern "C" void kernel_launch(void* const* d_in, const int* in_sizes, int n_in,
                              void* d_out, int out_size, void* d_ws, size_t ws_size,
                              hipStream_t stream) {
    const float* x = (const float*)d_in[0];
    float* out = (float*)d_out;
    float* wsf = (float*)d_ws;

    float*    sqPart   = wsf;
    unsigned* nPart    = (unsigned*)(wsf + 131072);
    unsigned* dirtyCnt = (unsigned*)(wsf + 147456);
    float*    inv      = wsf + 147520;
    int*      padArr   = (int*)(wsf + 147584);
    int*      dirtyLoc = (int*)(wsf + 147600);

    // only dirtyCnt needs zeroing (partials are written unconditionally)
    hipMemsetAsync((char*)d_ws + 147456 * 4, 0, 64, stream);

    mbn_pass1<<<GRID1, 256, 0, stream>>>(x, sqPart, nPart, dirtyCnt, dirtyLoc);
    mbn_finalize<<<1, 256, 0, stream>>>(x, sqPart, nPart, dirtyCnt, dirtyLoc, inv, padArr);
    mbn_pass2<<<8192, 256, 0, stream>>>((const float4*)x, (float4*)out, inv);
    mbn_fixup<<<1, 64, 0, stream>>>(x, out, dirtyCnt, dirtyLoc, padArr);
}